// Round 12
// baseline (839.021 us; speedup 1.0000x reference)
//
#include <hip/hip_runtime.h>
#include <hip/hip_bf16.h>
#include <stdint.h>

#define M_TOK 4096
#define DDIM  2048
#define HDIM  2816
#define NEXP  8
#define PMAX  10240     // 40 * 256 >= 8192 + 8*255
#define MAXTILES 40
#define NB1   22        // HDIM / 128 (gemm1 col blocks: 128 gate + 128 up interleaved)
#define NB2   16        // DDIM / 128 (gemm2 col blocks)
#define NKT1  32        // DDIM / 64
#define NKT2  44        // HDIM / 64

typedef __attribute__((ext_vector_type(8))) short short8;
typedef __attribute__((ext_vector_type(4))) float f32x4;

#define GLD16(g, l) __builtin_amdgcn_global_load_lds(                              \
    (const __attribute__((address_space(1))) unsigned int*)(g),                    \
    (__attribute__((address_space(3))) unsigned int*)(l), 16, 0, 0)

#define VMCNT(n) asm volatile("s_waitcnt vmcnt(" #n ")" ::: "memory")

__device__ __forceinline__ unsigned short f2bf(float f) {
  unsigned int u = __float_as_uint(f);
  u += 0x7fffu + ((u >> 16) & 1u);
  return (unsigned short)(u >> 16);
}
__device__ __forceinline__ float bf2f(unsigned short u) {
  return __uint_as_float(((unsigned)u) << 16);
}

// ---------------- fp32 -> bf16 bulk convert (w1+w2) + init fused ----------------
__global__ void cvt2_bf16_k(const float4* __restrict__ in1, ushort4* __restrict__ out1, int n1,
                            const float4* __restrict__ in2, ushort4* __restrict__ out2, int n2,
                            int* __restrict__ tok, int* __restrict__ counts,
                            int* __restrict__ cursors) {
  int gid = blockIdx.x * blockDim.x + threadIdx.x;
  if (gid < PMAX) tok[gid] = -1;
  if (gid < NEXP) { counts[gid] = 0; cursors[gid] = 0; }
  const int stride = gridDim.x * blockDim.x;
  const int total = n1 + n2;
  int i = gid;
  for (; i + stride < total; i += 2 * stride) {
    int ia = i, ib = i + stride;
    float4 va = (ia < n1) ? in1[ia] : in2[ia - n1];
    float4 vb = (ib < n1) ? in1[ib] : in2[ib - n1];
    ushort4 oa, ob;
    oa.x = f2bf(va.x); oa.y = f2bf(va.y); oa.z = f2bf(va.z); oa.w = f2bf(va.w);
    ob.x = f2bf(vb.x); ob.y = f2bf(vb.y); ob.z = f2bf(vb.z); ob.w = f2bf(vb.w);
    if (ia < n1) out1[ia] = oa; else out2[ia - n1] = oa;
    if (ib < n1) out1[ib] = ob; else out2[ib - n1] = ob;
  }
  if (i < total) {
    float4 v = (i < n1) ? in1[i] : in2[i - n1];
    ushort4 o;
    o.x = f2bf(v.x); o.y = f2bf(v.y); o.z = f2bf(v.z); o.w = f2bf(v.w);
    if (i < n1) out1[i] = o; else out2[i - n1] = o;
  }
}

// ---------------- router (fused x->bf16 conversion) ----------------
__global__ __launch_bounds__(256) void router_k(const float4* __restrict__ x4,
                                                const float4* __restrict__ rw4,
                                                ushort4* __restrict__ xb4,
                                                float* __restrict__ wgt,
                                                int* __restrict__ eid,
                                                int* __restrict__ counts) {
  int lane = threadIdx.x & 63;
  int wv = threadIdx.x >> 6;
  int t = blockIdx.x * 4 + wv;
  int base = t * (DDIM / 4);
  float acc[NEXP];
#pragma unroll
  for (int e = 0; e < NEXP; ++e) acc[e] = 0.f;
#pragma unroll
  for (int j = 0; j < DDIM / 4 / 64; ++j) {
    float4 v = x4[base + j * 64 + lane];
    ushort4 o;
    o.x = f2bf(v.x); o.y = f2bf(v.y); o.z = f2bf(v.z); o.w = f2bf(v.w);
    xb4[base + j * 64 + lane] = o;
#pragma unroll
    for (int e = 0; e < NEXP; ++e) {
      float4 w = rw4[e * (DDIM / 4) + j * 64 + lane];
      acc[e] += v.x * w.x + v.y * w.y + v.z * w.z + v.w * w.w;
    }
  }
#pragma unroll
  for (int e = 0; e < NEXP; ++e) {
#pragma unroll
    for (int s = 32; s > 0; s >>= 1) acc[e] += __shfl_xor(acc[e], s, 64);
  }
  if (lane == 0) {
    float mx = acc[0];
#pragma unroll
    for (int e = 1; e < NEXP; ++e) mx = fmaxf(mx, acc[e]);
    float p[NEXP];
#pragma unroll
    for (int e = 0; e < NEXP; ++e) p[e] = expf(acc[e] - mx);
    int e0 = 0; float p0 = p[0];
#pragma unroll
    for (int e = 1; e < NEXP; ++e) if (p[e] > p0) { p0 = p[e]; e0 = e; }
    int e1 = -1; float p1 = -1.f;
#pragma unroll
    for (int e = 0; e < NEXP; ++e) if (e != e0 && p[e] > p1) { p1 = p[e]; e1 = e; }
    float s = p0 + p1;
    wgt[2 * t] = p0 / s; wgt[2 * t + 1] = p1 / s;
    eid[2 * t] = e0;     eid[2 * t + 1] = e1;
    atomicAdd(&counts[e0], 1);
    atomicAdd(&counts[e1], 1);
  }
}

// ---------------- offsets + tile map + scatter (fused, single block) ----------------
__global__ __launch_bounds__(256) void offscat_k(const int* __restrict__ counts,
                                                 int* __restrict__ tile2exp,
                                                 int* __restrict__ tilerow,
                                                 int* __restrict__ ntiles,
                                                 const int* __restrict__ eid,
                                                 int* __restrict__ cursors,
                                                 int* __restrict__ tok,
                                                 int* __restrict__ slot) {
  __shared__ int soffs[NEXP];
  if (threadIdx.x == 0) {
    int o = 0, nt = 0;
    for (int e = 0; e < NEXP; ++e) {
      soffs[e] = o;
      int c = counts[e];
      int pt = (c + 255) >> 8;
      for (int i = 0; i < pt; ++i) { tile2exp[nt] = e; tilerow[nt] = o + i * 256; ++nt; }
      o += pt << 8;
    }
    ntiles[0] = nt;
  }
  __syncthreads();
  for (int t = threadIdx.x; t < M_TOK; t += 256) {
#pragma unroll
    for (int k = 0; k < 2; ++k) {
      int e = eid[2 * t + k];
      int p = soffs[e] + atomicAdd(&cursors[e], 1);
      tok[p] = t;
      slot[2 * t + k] = p;
    }
  }
}

// =============== GEMM1: 256 slots x (128 gate + 128 up interleaved), K=2048 ===============
// 512 thr (8 waves 2Mx4N), BK=64, 64KB LDS single-buffered -> 2 blocks/CU.
// B-tile: rows 0..127 = gate cols n0.., rows 128..255 = up cols n0..
// Wave wn's B fragments: ni<2 -> gate rows wn*32+ni*16; ni>=2 -> up rows
// 128+wn*32+(ni-2)*16, so silu(acc[ni])*acc[ni+2] is in-register (no LDS GLU).
__global__ __launch_bounds__(512, 2) void gemm1_k(const unsigned short* __restrict__ xb,
                                                  const unsigned short* __restrict__ w1b,
                                                  const int* __restrict__ tok,
                                                  const int* __restrict__ tile2exp,
                                                  const int* __restrict__ tilerow,
                                                  const int* __restrict__ ntiles,
                                                  unsigned short* __restrict__ h) {
  __shared__ char ldsp[65536];
  int mt = blockIdx.x;
  if (mt >= ntiles[0]) return;
  int e = tile2exp[mt], r0 = tilerow[mt];
  int n0 = blockIdx.y * 128;
  int tid = threadIdx.x, lane = tid & 63;
  int wv = tid >> 6, wm = wv >> 2, wn = wv & 3;
  int l15 = lane & 15, lq = lane >> 4;

  // staging: A rows srow+u*64 -> LDS[0..32KB); B same -> LDS[32KB..64KB)
  int srow = tid >> 3, sq = tid & 7;
  const char* aSrc[4]; const char* bSrc[4];
#pragma unroll
  for (int u = 0; u < 4; ++u) {
    int r = srow + u * 64;
    int t = tok[r0 + r]; if (t < 0) t = 0;
    aSrc[u] = (const char*)xb + (size_t)t * (DDIM * 2) + ((sq ^ (r & 7)) << 4);
    int w1row = e * (2 * HDIM) + (r < 128 ? n0 + r : HDIM + n0 + (r - 128));
    bSrc[u] = (const char*)w1b + (size_t)w1row * (DDIM * 2) + ((sq ^ (r & 7)) << 4);
  }

  int aoff[8], boff[4];
#pragma unroll
  for (int mi = 0; mi < 8; ++mi) {
    int r = wm * 128 + mi * 16 + l15;
    aoff[mi] = r * 128 + ((lq ^ (r & 7)) << 4);
  }
#pragma unroll
  for (int ni = 0; ni < 4; ++ni) {
    int r = (ni < 2) ? (wn * 32 + ni * 16 + l15)
                     : (128 + wn * 32 + (ni - 2) * 16 + l15);
    boff[ni] = r * 128 + ((lq ^ (r & 7)) << 4);
  }

  f32x4 acc[8][4];
#pragma unroll
  for (int mi = 0; mi < 8; ++mi)
#pragma unroll
    for (int ni = 0; ni < 4; ++ni) acc[mi][ni] = (f32x4)(0.f);

#pragma unroll 1
  for (int kt = 0; kt < NKT1; ++kt) {
    __syncthreads();
    size_t kb = (size_t)kt * 128;
#pragma unroll
    for (int u = 0; u < 4; ++u) {
      GLD16(aSrc[u] + kb, ldsp + u * 8192 + tid * 16);
      GLD16(bSrc[u] + kb, ldsp + 32768 + u * 8192 + tid * 16);
    }
    VMCNT(0);
    __syncthreads();
#pragma unroll
    for (int s = 0; s < 2; ++s) {
      int sx = s << 6;
      short8 a[8], b[4];
#pragma unroll
      for (int i = 0; i < 8; ++i) a[i] = *(const short8*)(ldsp + (aoff[i] ^ sx));
#pragma unroll
      for (int i = 0; i < 4; ++i) b[i] = *(const short8*)(ldsp + 32768 + (boff[i] ^ sx));
      __builtin_amdgcn_s_setprio(1);
#pragma unroll
      for (int mi = 0; mi < 8; ++mi)
#pragma unroll
        for (int ni = 0; ni < 4; ++ni)
          acc[mi][ni] = __builtin_amdgcn_mfma_f32_16x16x32_bf16(a[mi], b[ni], acc[mi][ni], 0, 0, 0);
      __builtin_amdgcn_s_setprio(0);
    }
  }

  // in-register GLU epilogue: gate = acc[.][ni], up = acc[.][ni+2]
#pragma unroll
  for (int mi = 0; mi < 8; ++mi)
#pragma unroll
    for (int ni = 0; ni < 2; ++ni)
#pragma unroll
      for (int j = 0; j < 4; ++j) {
        int r = wm * 128 + mi * 16 + lq * 4 + j;
        int c = n0 + wn * 32 + ni * 16 + l15;
        float gg = acc[mi][ni][j];
        float u = acc[mi][ni + 2][j];
        float sv = gg / (1.f + expf(-gg));
        h[(size_t)(r0 + r) * HDIM + c] = f2bf(sv * u);
      }
}

// =============== GEMM2: m97-style, 256 rows x 128 D-cols, BK=64 (R10, control) ===============
__global__ __launch_bounds__(256, 2) void gemm2_k(const unsigned short* __restrict__ h,
                                                  const unsigned short* __restrict__ w2b,
                                                  const int* __restrict__ tile2exp,
                                                  const int* __restrict__ tilerow,
                                                  const int* __restrict__ ntiles,
                                                  unsigned short* __restrict__ yp) {
  __shared__ char ldsp[49152];
  int mt = blockIdx.x;
  if (mt >= ntiles[0]) return;
  int e = tile2exp[mt], r0 = tilerow[mt];
  int n0 = blockIdx.y * 128;
  int tid = threadIdx.x, lane = tid & 63;
  int wv = tid >> 6, wm = wv >> 1, wn = wv & 1;
  int l15 = lane & 15, lq = lane >> 4;

  int sg = tid & 7, srow = tid >> 3;
  unsigned int aOff[8], bOff[4];
#pragma unroll
  for (int j = 0; j < 8; ++j) {
    int r = j * 32 + srow;
    aOff[j] = (unsigned int)(r0 + r) * (HDIM * 2) + (unsigned int)((sg ^ (r & 7)) << 4);
  }
#pragma unroll
  for (int j = 0; j < 4; ++j) {
    int r = j * 32 + srow;
    bOff[j] = (unsigned int)(e * DDIM + n0 + r) * (HDIM * 2) + (unsigned int)((sg ^ (r & 7)) << 4);
  }

  int aRd[8], bRd[4];
#pragma unroll
  for (int i = 0; i < 8; ++i) {
    int r = wm * 128 + i * 16 + l15;
    aRd[i] = r * 128 + ((lq ^ (r & 7)) << 4);
  }
#pragma unroll
  for (int i = 0; i < 4; ++i) {
    int r = wn * 64 + i * 16 + l15;
    bRd[i] = r * 128 + ((lq ^ (r & 7)) << 4);
  }

  f32x4 acc[8][4];
#pragma unroll
  for (int mi = 0; mi < 8; ++mi)
#pragma unroll
    for (int ni = 0; ni < 4; ++ni) acc[mi][ni] = (f32x4)(0.f);

  const char* hB = (const char*)h;
  const char* wB = (const char*)w2b;

#pragma unroll 1
  for (int kt = 0; kt < NKT2; ++kt) {
    __syncthreads();
    unsigned int kb = (unsigned int)kt * 128;
#pragma unroll
    for (int j = 0; j < 8; ++j) GLD16(hB + aOff[j] + kb, ldsp + j * 4096 + tid * 16);
#pragma unroll
    for (int j = 0; j < 4; ++j) GLD16(wB + bOff[j] + kb, ldsp + 32768 + j * 4096 + tid * 16);
    VMCNT(0);
    __syncthreads();
#pragma unroll
    for (int kh = 0; kh < 2; ++kh) {
      int kx = kh << 6;
      short8 a[8], b[4];
#pragma unroll
      for (int i = 0; i < 8; ++i) a[i] = *(const short8*)(ldsp + (aRd[i] ^ kx));
#pragma unroll
      for (int i = 0; i < 4; ++i) b[i] = *(const short8*)(ldsp + 32768 + (bRd[i] ^ kx));
      __builtin_amdgcn_s_setprio(1);
#pragma unroll
      for (int mi = 0; mi < 8; ++mi)
#pragma unroll
        for (int ni = 0; ni < 4; ++ni)
          acc[mi][ni] = __builtin_amdgcn_mfma_f32_16x16x32_bf16(a[mi], b[ni], acc[mi][ni], 0, 0, 0);
      __builtin_amdgcn_s_setprio(0);
    }
  }

#pragma unroll
  for (int mi = 0; mi < 8; ++mi)
#pragma unroll
    for (int ni = 0; ni < 4; ++ni)
#pragma unroll
      for (int j = 0; j < 4; ++j) {
        int r = r0 + wm * 128 + mi * 16 + lq * 4 + j;
        int c = n0 + wn * 64 + ni * 16 + l15;
        yp[(size_t)r * DDIM + c] = f2bf(acc[mi][ni][j]);
      }
}

// ---------------- combine: y = w0*yp[s0] + w1*yp[s1] + bias ----------------
__global__ void combine_k(const unsigned short* __restrict__ yp, const float* __restrict__ wgt,
                          const int* __restrict__ slot, const float* __restrict__ bias,
                          float* __restrict__ out) {
  int idx = blockIdx.x * blockDim.x + threadIdx.x;
  int t = idx >> 8, q = (idx & 255) * 8;
  float w0 = wgt[2 * t], w1 = wgt[2 * t + 1];
  int s0 = slot[2 * t], s1 = slot[2 * t + 1];
  short8 a8 = *(const short8*)(yp + (size_t)s0 * DDIM + q);
  short8 b8 = *(const short8*)(yp + (size_t)s1 * DDIM + q);
  float* op = out + (size_t)t * DDIM + q;
#pragma unroll
  for (int k = 0; k < 8; ++k) {
    float av = bf2f((unsigned short)a8[k]);
    float bv = bf2f((unsigned short)b8[k]);
    op[k] = w0 * av + w1 * bv + bias[q + k];
  }
}

extern "C" void kernel_launch(void* const* d_in, const int* in_sizes, int n_in,
                              void* d_out, int out_size, void* d_ws, size_t ws_size,
                              hipStream_t stream) {
  const float* x    = (const float*)d_in[0];
  const float* w1   = (const float*)d_in[1];
  const float* w2   = (const float*)d_in[2];
  const float* rw   = (const float*)d_in[3];
  const float* bias = (const float*)d_in[4];
  float* out = (float*)d_out;

  char* ws = (char*)d_ws;
  size_t off = 0;
  auto alloc = [&](size_t bytes) -> void* {
    void* p = ws + off;
    off = (off + bytes + 255) & ~(size_t)255;
    return p;
  };
  unsigned short* w1b = (unsigned short*)alloc((size_t)NEXP * 2 * HDIM * DDIM * 2);
  unsigned short* w2b = (unsigned short*)alloc((size_t)NEXP * DDIM * HDIM * 2);
  unsigned short* xb  = (unsigned short*)alloc((size_t)M_TOK * DDIM * 2);
  unsigned short* h   = (unsigned short*)alloc((size_t)PMAX * HDIM * 2);
  unsigned short* yp  = (unsigned short*)alloc((size_t)PMAX * DDIM * 2);
  float* wgt          = (float*)alloc((size_t)M_TOK * 2 * 4);
  int* eid            = (int*)alloc((size_t)M_TOK * 2 * 4);
  int* slot           = (int*)alloc((size_t)M_TOK * 2 * 4);
  int* tok            = (int*)alloc((size_t)PMAX * 4);
  int* counts         = (int*)alloc(64 * 4);
  int* cursors        = (int*)alloc(64 * 4);
  int* ntiles         = (int*)alloc(64 * 4);
  int* tile2exp       = (int*)alloc(128 * 4);
  int* tilerow        = (int*)alloc(128 * 4);

  hipLaunchKernelGGL(cvt2_bf16_k, dim3(4096), dim3(256), 0, stream,
                     (const float4*)w1, (ushort4*)w1b, (int)((size_t)NEXP * 2 * HDIM * DDIM / 4),
                     (const float4*)w2, (ushort4*)w2b, (int)((size_t)NEXP * DDIM * HDIM / 4),
                     tok, counts, cursors);
  hipLaunchKernelGGL(router_k, dim3(M_TOK / 4), dim3(256), 0, stream,
                     (const float4*)x, (const float4*)rw, (ushort4*)xb, wgt, eid, counts);
  hipLaunchKernelGGL(offscat_k, dim3(1), dim3(256), 0, stream,
                     counts, tile2exp, tilerow, ntiles, eid, cursors, tok, slot);
  hipLaunchKernelGGL(gemm1_k, dim3(MAXTILES, NB1), dim3(512), 0, stream,
                     xb, w1b, tok, tile2exp, tilerow, ntiles, h);
  hipLaunchKernelGGL(gemm2_k, dim3(MAXTILES, NB2), dim3(256), 0, stream,
                     h, w2b, tile2exp, tilerow, ntiles, yp);
  hipLaunchKernelGGL(combine_k, dim3(M_TOK * (DDIM / 8) / 256), dim3(256), 0, stream, yp, wgt, slot, bias, out);
}

// Round 13
// 746.035 us; speedup vs baseline: 1.1246x; 1.1246x over previous
//
#include <hip/hip_runtime.h>
#include <hip/hip_bf16.h>
#include <stdint.h>

#define M_TOK 4096
#define DDIM  2048
#define HDIM  2816
#define NEXP  8
#define PMAX  10240     // 40 * 256 >= 8192 + 8*255
#define MAXTILES 40
#define NB1   44        // HDIM / 64 col blocks (gemm1: 64 gate + 64 up each)
#define NB2   16        // DDIM / 128 col blocks (gemm2)
#define NKT1  32        // DDIM / 64
#define NKT2  44        // HDIM / 64

typedef __attribute__((ext_vector_type(8))) short short8;
typedef __attribute__((ext_vector_type(4))) float f32x4;

#define GLD16(g, l) __builtin_amdgcn_global_load_lds(                              \
    (const __attribute__((address_space(1))) unsigned int*)(g),                    \
    (__attribute__((address_space(3))) unsigned int*)(l), 16, 0, 0)

#define VMCNT(n) asm volatile("s_waitcnt vmcnt(" #n ")" ::: "memory")

__device__ __forceinline__ unsigned short f2bf(float f) {
  unsigned int u = __float_as_uint(f);
  u += 0x7fffu + ((u >> 16) & 1u);
  return (unsigned short)(u >> 16);
}
__device__ __forceinline__ float bf2f(unsigned short u) {
  return __uint_as_float(((unsigned)u) << 16);
}

// ---------------- fp32 -> bf16 bulk convert, plain streaming ----------------
// doinit != 0 on the first launch folds the tok/counts/cursors init in.
__global__ void cvt_bf16_k(const float4* __restrict__ in, ushort4* __restrict__ out, int n4,
                           int* __restrict__ tok, int* __restrict__ counts,
                           int* __restrict__ cursors, int doinit) {
  int gid = blockIdx.x * blockDim.x + threadIdx.x;
  if (doinit) {
    if (gid < PMAX) tok[gid] = -1;
    if (gid < NEXP) { counts[gid] = 0; cursors[gid] = 0; }
  }
  int stride = gridDim.x * blockDim.x;
  for (int i = gid; i < n4; i += stride) {
    float4 v = in[i];
    ushort4 o;
    o.x = f2bf(v.x); o.y = f2bf(v.y); o.z = f2bf(v.z); o.w = f2bf(v.w);
    out[i] = o;
  }
}

// ---------------- router (fused x->bf16 conversion; R10 verbatim) ----------------
__global__ __launch_bounds__(256) void router_k(const float4* __restrict__ x4,
                                                const float4* __restrict__ rw4,
                                                ushort4* __restrict__ xb4,
                                                float* __restrict__ wgt,
                                                int* __restrict__ eid,
                                                int* __restrict__ counts) {
  int lane = threadIdx.x & 63;
  int wv = threadIdx.x >> 6;
  int t = blockIdx.x * 4 + wv;
  int base = t * (DDIM / 4);
  float acc[NEXP];
#pragma unroll
  for (int e = 0; e < NEXP; ++e) acc[e] = 0.f;
#pragma unroll
  for (int j = 0; j < DDIM / 4 / 64; ++j) {
    float4 v = x4[base + j * 64 + lane];
    ushort4 o;
    o.x = f2bf(v.x); o.y = f2bf(v.y); o.z = f2bf(v.z); o.w = f2bf(v.w);
    xb4[base + j * 64 + lane] = o;
#pragma unroll
    for (int e = 0; e < NEXP; ++e) {
      float4 w = rw4[e * (DDIM / 4) + j * 64 + lane];
      acc[e] += v.x * w.x + v.y * w.y + v.z * w.z + v.w * w.w;
    }
  }
#pragma unroll
  for (int e = 0; e < NEXP; ++e) {
#pragma unroll
    for (int s = 32; s > 0; s >>= 1) acc[e] += __shfl_xor(acc[e], s, 64);
  }
  if (lane == 0) {
    float mx = acc[0];
#pragma unroll
    for (int e = 1; e < NEXP; ++e) mx = fmaxf(mx, acc[e]);
    float p[NEXP];
#pragma unroll
    for (int e = 0; e < NEXP; ++e) p[e] = expf(acc[e] - mx);
    int e0 = 0; float p0 = p[0];
#pragma unroll
    for (int e = 1; e < NEXP; ++e) if (p[e] > p0) { p0 = p[e]; e0 = e; }
    int e1 = -1; float p1 = -1.f;
#pragma unroll
    for (int e = 0; e < NEXP; ++e) if (e != e0 && p[e] > p1) { p1 = p[e]; e1 = e; }
    float s = p0 + p1;
    wgt[2 * t] = p0 / s; wgt[2 * t + 1] = p1 / s;
    eid[2 * t] = e0;     eid[2 * t + 1] = e1;
    atomicAdd(&counts[e0], 1);
    atomicAdd(&counts[e1], 1);
  }
}

// ---------------- offsets + tile map + scatter (fused; R12 verbatim) ----------------
__global__ __launch_bounds__(256) void offscat_k(const int* __restrict__ counts,
                                                 int* __restrict__ tile2exp,
                                                 int* __restrict__ tilerow,
                                                 int* __restrict__ ntiles,
                                                 const int* __restrict__ eid,
                                                 int* __restrict__ cursors,
                                                 int* __restrict__ tok,
                                                 int* __restrict__ slot) {
  __shared__ int soffs[NEXP];
  if (threadIdx.x == 0) {
    int o = 0, nt = 0;
    for (int e = 0; e < NEXP; ++e) {
      soffs[e] = o;
      int c = counts[e];
      int pt = (c + 255) >> 8;
      for (int i = 0; i < pt; ++i) { tile2exp[nt] = e; tilerow[nt] = o + i * 256; ++nt; }
      o += pt << 8;
    }
    ntiles[0] = nt;
  }
  __syncthreads();
  for (int t = threadIdx.x; t < M_TOK; t += 256) {
#pragma unroll
    for (int k = 0; k < 2; ++k) {
      int e = eid[2 * t + k];
      int p = soffs[e] + atomicAdd(&cursors[e], 1);
      tok[p] = t;
      slot[2 * t + k] = p;
    }
  }
}

// =============== GEMM1: m97-style, 256 rows x (64 gate + 64 up), BK=64 (R10 verbatim, 276us) ===============
__global__ __launch_bounds__(256, 2) void gemm1_k(const unsigned short* __restrict__ xb,
                                                  const unsigned short* __restrict__ w1b,
                                                  const int* __restrict__ tok,
                                                  const int* __restrict__ tile2exp,
                                                  const int* __restrict__ tilerow,
                                                  const int* __restrict__ ntiles,
                                                  unsigned short* __restrict__ h) {
  __shared__ char ldsp[65536];
  int mt = blockIdx.x;
  if (mt >= ntiles[0]) return;
  int e = tile2exp[mt], r0 = tilerow[mt];
  int n0 = blockIdx.y * 64;
  int tid = threadIdx.x, lane = tid & 63;
  int wv = tid >> 6, wm = wv >> 1, wn = wv & 1;
  int l15 = lane & 15, lq = lane >> 4;

  int sg = tid & 7, srow = tid >> 3;   // srow 0..31
  unsigned int aOff[8], bOff[4];
#pragma unroll
  for (int j = 0; j < 8; ++j) {
    int r = j * 32 + srow;
    int t = tok[r0 + r]; if (t < 0) t = 0;
    aOff[j] = (unsigned int)t * (DDIM * 2) + (unsigned int)((sg ^ (r & 7)) << 4);
  }
#pragma unroll
  for (int j = 0; j < 4; ++j) {
    int r = j * 32 + srow;           // 0..63 gate cols, 64..127 up cols
    int w1row = e * (2 * HDIM) + (r < 64 ? n0 + r : HDIM + n0 + (r - 64));
    bOff[j] = (unsigned int)w1row * (DDIM * 2) + (unsigned int)((sg ^ (r & 7)) << 4);
  }

  int aRd[8], bRd[4];
#pragma unroll
  for (int i = 0; i < 8; ++i) {
    int r = wm * 128 + i * 16 + l15;
    aRd[i] = r * 128 + ((lq ^ (r & 7)) << 4);
  }
#pragma unroll
  for (int i = 0; i < 4; ++i) {
    int r = wn * 64 + i * 16 + l15;
    bRd[i] = r * 128 + ((lq ^ (r & 7)) << 4);
  }

  f32x4 acc[8][4];
#pragma unroll
  for (int mi = 0; mi < 8; ++mi)
#pragma unroll
    for (int ni = 0; ni < 4; ++ni) acc[mi][ni] = (f32x4)(0.f);

  const char* xB = (const char*)xb;
  const char* wB = (const char*)w1b;

#pragma unroll 1
  for (int kt = 0; kt < NKT1; ++kt) {
    __syncthreads();
    unsigned int kb = (unsigned int)kt * 128;
#pragma unroll
    for (int j = 0; j < 8; ++j) GLD16(xB + aOff[j] + kb, ldsp + j * 4096 + tid * 16);
#pragma unroll
    for (int j = 0; j < 4; ++j) GLD16(wB + bOff[j] + kb, ldsp + 32768 + j * 4096 + tid * 16);
    VMCNT(0);
    __syncthreads();
#pragma unroll
    for (int kh = 0; kh < 2; ++kh) {
      int kx = kh << 6;
      short8 a[8], b[4];
#pragma unroll
      for (int i = 0; i < 8; ++i) a[i] = *(const short8*)(ldsp + (aRd[i] ^ kx));
#pragma unroll
      for (int i = 0; i < 4; ++i) b[i] = *(const short8*)(ldsp + 32768 + (bRd[i] ^ kx));
      __builtin_amdgcn_s_setprio(1);
#pragma unroll
      for (int mi = 0; mi < 8; ++mi)
#pragma unroll
        for (int ni = 0; ni < 4; ++ni)
          acc[mi][ni] = __builtin_amdgcn_mfma_f32_16x16x32_bf16(a[mi], b[ni], acc[mi][ni], 0, 0, 0);
      __builtin_amdgcn_s_setprio(0);
    }
  }

  // GLU epilogue: up wave -> LDS f32 [256][64] (lq-XOR swizzle), gate wave reads
  __syncthreads();
  float* xch = (float*)ldsp;
  if (wn == 1) {
#pragma unroll
    for (int mi = 0; mi < 8; ++mi)
#pragma unroll
      for (int ni = 0; ni < 4; ++ni)
#pragma unroll
        for (int j = 0; j < 4; ++j) {
          int r = wm * 128 + mi * 16 + lq * 4 + j;
          int c = ni * 16 + l15;
          xch[r * 64 + (c ^ (lq << 2))] = acc[mi][ni][j];
        }
  }
  __syncthreads();
  if (wn == 0) {
#pragma unroll
    for (int mi = 0; mi < 8; ++mi)
#pragma unroll
      for (int ni = 0; ni < 4; ++ni)
#pragma unroll
        for (int j = 0; j < 4; ++j) {
          int r = wm * 128 + mi * 16 + lq * 4 + j;
          int c = ni * 16 + l15;
          float u = xch[r * 64 + (c ^ (lq << 2))];
          float gg = acc[mi][ni][j];
          float sv = gg / (1.f + expf(-gg));
          h[(size_t)(r0 + r) * HDIM + n0 + c] = f2bf(sv * u);
        }
  }
}

// =============== GEMM2: m97-style, 256 rows x 128 D-cols, BK=64 (R10 verbatim, ~140us) ===============
__global__ __launch_bounds__(256, 2) void gemm2_k(const unsigned short* __restrict__ h,
                                                  const unsigned short* __restrict__ w2b,
                                                  const int* __restrict__ tile2exp,
                                                  const int* __restrict__ tilerow,
                                                  const int* __restrict__ ntiles,
                                                  unsigned short* __restrict__ yp) {
  __shared__ char ldsp[49152];
  int mt = blockIdx.x;
  if (mt >= ntiles[0]) return;
  int e = tile2exp[mt], r0 = tilerow[mt];
  int n0 = blockIdx.y * 128;
  int tid = threadIdx.x, lane = tid & 63;
  int wv = tid >> 6, wm = wv >> 1, wn = wv & 1;
  int l15 = lane & 15, lq = lane >> 4;

  int sg = tid & 7, srow = tid >> 3;
  unsigned int aOff[8], bOff[4];
#pragma unroll
  for (int j = 0; j < 8; ++j) {
    int r = j * 32 + srow;
    aOff[j] = (unsigned int)(r0 + r) * (HDIM * 2) + (unsigned int)((sg ^ (r & 7)) << 4);
  }
#pragma unroll
  for (int j = 0; j < 4; ++j) {
    int r = j * 32 + srow;
    bOff[j] = (unsigned int)(e * DDIM + n0 + r) * (HDIM * 2) + (unsigned int)((sg ^ (r & 7)) << 4);
  }

  int aRd[8], bRd[4];
#pragma unroll
  for (int i = 0; i < 8; ++i) {
    int r = wm * 128 + i * 16 + l15;
    aRd[i] = r * 128 + ((lq ^ (r & 7)) << 4);
  }
#pragma unroll
  for (int i = 0; i < 4; ++i) {
    int r = wn * 64 + i * 16 + l15;
    bRd[i] = r * 128 + ((lq ^ (r & 7)) << 4);
  }

  f32x4 acc[8][4];
#pragma unroll
  for (int mi = 0; mi < 8; ++mi)
#pragma unroll
    for (int ni = 0; ni < 4; ++ni) acc[mi][ni] = (f32x4)(0.f);

  const char* hB = (const char*)h;
  const char* wB = (const char*)w2b;

#pragma unroll 1
  for (int kt = 0; kt < NKT2; ++kt) {
    __syncthreads();
    unsigned int kb = (unsigned int)kt * 128;
#pragma unroll
    for (int j = 0; j < 8; ++j) GLD16(hB + aOff[j] + kb, ldsp + j * 4096 + tid * 16);
#pragma unroll
    for (int j = 0; j < 4; ++j) GLD16(wB + bOff[j] + kb, ldsp + 32768 + j * 4096 + tid * 16);
    VMCNT(0);
    __syncthreads();
#pragma unroll
    for (int kh = 0; kh < 2; ++kh) {
      int kx = kh << 6;
      short8 a[8], b[4];
#pragma unroll
      for (int i = 0; i < 8; ++i) a[i] = *(const short8*)(ldsp + (aRd[i] ^ kx));
#pragma unroll
      for (int i = 0; i < 4; ++i) b[i] = *(const short8*)(ldsp + 32768 + (bRd[i] ^ kx));
      __builtin_amdgcn_s_setprio(1);
#pragma unroll
      for (int mi = 0; mi < 8; ++mi)
#pragma unroll
        for (int ni = 0; ni < 4; ++ni)
          acc[mi][ni] = __builtin_amdgcn_mfma_f32_16x16x32_bf16(a[mi], b[ni], acc[mi][ni], 0, 0, 0);
      __builtin_amdgcn_s_setprio(0);
    }
  }

#pragma unroll
  for (int mi = 0; mi < 8; ++mi)
#pragma unroll
    for (int ni = 0; ni < 4; ++ni)
#pragma unroll
      for (int j = 0; j < 4; ++j) {
        int r = r0 + wm * 128 + mi * 16 + lq * 4 + j;
        int c = n0 + wn * 64 + ni * 16 + l15;
        yp[(size_t)r * DDIM + c] = f2bf(acc[mi][ni][j]);
      }
}

// ---------------- combine: y = w0*yp[s0] + w1*yp[s1] + bias ----------------
__global__ void combine_k(const unsigned short* __restrict__ yp, const float* __restrict__ wgt,
                          const int* __restrict__ slot, const float* __restrict__ bias,
                          float* __restrict__ out) {
  int idx = blockIdx.x * blockDim.x + threadIdx.x;
  int t = idx >> 8, q = (idx & 255) * 8;
  float w0 = wgt[2 * t], w1 = wgt[2 * t + 1];
  int s0 = slot[2 * t], s1 = slot[2 * t + 1];
  short8 a8 = *(const short8*)(yp + (size_t)s0 * DDIM + q);
  short8 b8 = *(const short8*)(yp + (size_t)s1 * DDIM + q);
  float* op = out + (size_t)t * DDIM + q;
#pragma unroll
  for (int k = 0; k < 8; ++k) {
    float av = bf2f((unsigned short)a8[k]);
    float bv = bf2f((unsigned short)b8[k]);
    op[k] = w0 * av + w1 * bv + bias[q + k];
  }
}

extern "C" void kernel_launch(void* const* d_in, const int* in_sizes, int n_in,
                              void* d_out, int out_size, void* d_ws, size_t ws_size,
                              hipStream_t stream) {
  const float* x    = (const float*)d_in[0];
  const float* w1   = (const float*)d_in[1];
  const float* w2   = (const float*)d_in[2];
  const float* rw   = (const float*)d_in[3];
  const float* bias = (const float*)d_in[4];
  float* out = (float*)d_out;

  char* ws = (char*)d_ws;
  size_t off = 0;
  auto alloc = [&](size_t bytes) -> void* {
    void* p = ws + off;
    off = (off + bytes + 255) & ~(size_t)255;
    return p;
  };
  unsigned short* w1b = (unsigned short*)alloc((size_t)NEXP * 2 * HDIM * DDIM * 2);
  unsigned short* w2b = (unsigned short*)alloc((size_t)NEXP * DDIM * HDIM * 2);
  unsigned short* xb  = (unsigned short*)alloc((size_t)M_TOK * DDIM * 2);
  unsigned short* h   = (unsigned short*)alloc((size_t)PMAX * HDIM * 2);
  unsigned short* yp  = (unsigned short*)alloc((size_t)PMAX * DDIM * 2);
  float* wgt          = (float*)alloc((size_t)M_TOK * 2 * 4);
  int* eid            = (int*)alloc((size_t)M_TOK * 2 * 4);
  int* slot           = (int*)alloc((size_t)M_TOK * 2 * 4);
  int* tok            = (int*)alloc((size_t)PMAX * 4);
  int* counts         = (int*)alloc(64 * 4);
  int* cursors        = (int*)alloc(64 * 4);
  int* ntiles         = (int*)alloc(64 * 4);
  int* tile2exp       = (int*)alloc(128 * 4);
  int* tilerow        = (int*)alloc(128 * 4);

  const int n1 = (int)((size_t)NEXP * 2 * HDIM * DDIM / 4);
  const int n2 = (int)((size_t)NEXP * DDIM * HDIM / 4);
  hipLaunchKernelGGL(cvt_bf16_k, dim3(2048), dim3(256), 0, stream,
                     (const float4*)w1, (ushort4*)w1b, n1, tok, counts, cursors, 1);
  hipLaunchKernelGGL(cvt_bf16_k, dim3(2048), dim3(256), 0, stream,
                     (const float4*)w2, (ushort4*)w2b, n2, tok, counts, cursors, 0);
  hipLaunchKernelGGL(router_k, dim3(M_TOK / 4), dim3(256), 0, stream,
                     (const float4*)x, (const float4*)rw, (ushort4*)xb, wgt, eid, counts);
  hipLaunchKernelGGL(offscat_k, dim3(1), dim3(256), 0, stream,
                     counts, tile2exp, tilerow, ntiles, eid, cursors, tok, slot);
  hipLaunchKernelGGL(gemm1_k, dim3(MAXTILES, NB1), dim3(256), 0, stream,
                     xb, w1b, tok, tile2exp, tilerow, ntiles, h);
  hipLaunchKernelGGL(gemm2_k, dim3(MAXTILES, NB2), dim3(256), 0, stream,
                     h, w2b, tile2exp, tilerow, ntiles, yp);
  hipLaunchKernelGGL(combine_k, dim3(M_TOK * (DDIM / 8) / 256), dim3(256), 0, stream, yp, wgt, slot, bias, out);
}